// Round 5
// baseline (427.291 us; speedup 1.0000x reference)
//
#include <hip/hip_runtime.h>
#include <hip/hip_bf16.h>

// SimpleRetention on MI355X — round 5.
// K0: fused QKV gemm — X staged once (swizzled LDS), B-frags from L2-resident
//     WT (register double-buffer), mfma_f32_32x32x16_f16. NEW: epilogue stages
//     Q/K (post-xpos) and V^T through LDS so ALL global stores are coalesced
//     16B — fixes round-4's 6.8x HBM write amplification (342 MB vs 50 MB).
// K1: retention (unchanged from round 4): TK=64, async global_load_lds into
//     swizzled tiles, S^T=K*Q^T operand swap, 32x32x16 MFMA, sc aliases ksb.

#define S_LEN 2048
#define HD 256
#define BN 16

typedef _Float16 half8 __attribute__((ext_vector_type(8)));
typedef _Float16 half4 __attribute__((ext_vector_type(4)));
typedef float floatx16 __attribute__((ext_vector_type(16)));

__device__ __forceinline__ void gl_lds16(const void* g, void* l) {
  __builtin_amdgcn_global_load_lds(
      (const __attribute__((address_space(1))) unsigned int*)(unsigned long long)g,
      (__attribute__((address_space(3))) unsigned int*)(unsigned int)(unsigned long long)l,
      16, 0, 0);
}

// ---------------- Kernel P: W transpose fp32 -> f16 [w][n][k] ----------------
__global__ __launch_bounds__(256) void wprep_kernel(
    const float* __restrict__ WQ, const float* __restrict__ WK,
    const float* __restrict__ WV, _Float16* __restrict__ WT) {
  __shared__ _Float16 trans[64][72];
  const int tid = threadIdx.x;
  const int w = blockIdx.y;
  const int tk = (blockIdx.x & 3) * 64;
  const int tn = (blockIdx.x >> 2) * 64;
  const float* W = (w == 0) ? WQ : (w == 1) ? WK : WV;
#pragma unroll
  for (int u = 0; u < 4; ++u) {
    int idx = u * 256 + tid;
    int k = idx >> 4;
    int nq = (idx & 15) * 4;
    float4 v = *(const float4*)&W[(tk + k) * HD + tn + nq];
    trans[nq + 0][k] = (_Float16)v.x;
    trans[nq + 1][k] = (_Float16)v.y;
    trans[nq + 2][k] = (_Float16)v.z;
    trans[nq + 3][k] = (_Float16)v.w;
  }
  __syncthreads();
#pragma unroll
  for (int u = 0; u < 2; ++u) {
    int idx = u * 256 + tid;
    int n = idx >> 3;
    int kq = (idx & 7) * 8;
    *(uint4*)&WT[((long)w * HD + tn + n) * HD + tk + kq] = *(const uint4*)&trans[n][kq];
  }
}

// ---------------- Kernel 0: fused QKV projection + xpos ----------------
__global__ __launch_bounds__(256) void gemm_qkv_kernel(
    const float* __restrict__ X, const _Float16* __restrict__ WT,
    _Float16* __restrict__ Q, _Float16* __restrict__ K,
    _Float16* __restrict__ VT) {
  // xs @0 (32KB): X tile, 64 rows x 512B, chunk p = c ^ (row&31)
  // stg @32768 (32KB): Q/K store staging, same swizzle
  // vt @0 (36.9KB): V^T staging [256][72] f16 — only after final MFMA barrier
  __shared__ __align__(16) unsigned char smem[65536];
  unsigned char* stg = smem + 32768;

  const int tid = threadIdx.x;
  const int lane = tid & 63;
  const int w = tid >> 6;
  const int l31 = lane & 31;
  const int lh = lane >> 5;
  const int m0 = blockIdx.x * 64;
  const int mtile = w & 1;
  const int nhalf = w >> 1;

  // stage X (64 rows x 256 fp32) -> f16 swizzled
#pragma unroll
  for (int i = 0; i < 8; ++i) {
    int id = i * 256 + tid;
    int row = id >> 5, c = id & 31;
    int p = c ^ (row & 31);
    const float4* s = (const float4*)&X[(long)(m0 + row) * HD + c * 8];
    float4 v0 = s[0], v1 = s[1];
    half8 h;
    h[0] = (_Float16)v0.x; h[1] = (_Float16)v0.y;
    h[2] = (_Float16)v0.z; h[3] = (_Float16)v0.w;
    h[4] = (_Float16)v1.x; h[5] = (_Float16)v1.y;
    h[6] = (_Float16)v1.z; h[7] = (_Float16)v1.w;
    *(half8*)(smem + row * 512 + p * 16) = h;
  }
  __syncthreads();

  const int bn = m0 >> 11;
  const int mrow = mtile * 32 + l31;
  const int nbase = nhalf * 128;

  for (int wsel = 0; wsel < 3; ++wsel) {
    const _Float16* Wb = WT + (long)wsel * HD * HD;
    floatx16 acc[4];
#pragma unroll
    for (int nt = 0; nt < 4; ++nt)
#pragma unroll
      for (int e = 0; e < 16; ++e) acc[nt][e] = 0.f;

    half8 bcur[4], bnxt[4];
#pragma unroll
    for (int nt = 0; nt < 4; ++nt)
      bcur[nt] = *(const half8*)(Wb + (long)(nbase + nt * 32 + l31) * HD + lh * 8);
#pragma unroll
    for (int ks16 = 0; ks16 < 16; ++ks16) {
      int p = (ks16 * 2 + lh) ^ l31;
      half8 af = *(const half8*)(smem + mrow * 512 + p * 16);
      if (ks16 < 15) {
#pragma unroll
        for (int nt = 0; nt < 4; ++nt)
          bnxt[nt] = *(const half8*)(Wb + (long)(nbase + nt * 32 + l31) * HD +
                                     (ks16 + 1) * 16 + lh * 8);
      }
#pragma unroll
      for (int nt = 0; nt < 4; ++nt)
        acc[nt] = __builtin_amdgcn_mfma_f32_32x32x16_f16(af, bcur[nt], acc[nt], 0, 0, 0);
#pragma unroll
      for (int nt = 0; nt < 4; ++nt) bcur[nt] = bnxt[nt];
    }

    if (wsel < 2) {
      // xpos in regs (C-layout: col = nbase+nt*32+l31, partner = lane^1),
      // then stage rows in swizzled stg and store coalesced 16B.
      _Float16* o = wsel ? K : Q;
      const float esgn = wsel ? -1.0f : 1.0f;  // Q upscale, K downscale
      const int srow0 = (m0 & (S_LEN - 1)) + mtile * 32;
      _Float16 vals[4][16];
#pragma unroll
      for (int nt = 0; nt < 4; ++nt) {
        int col = nbase + nt * 32 + l31;
        int i2 = col >> 1;
        float inv_freq = exp2f(-(float)i2 * (13.287712379549449f / 128.0f));
        float lbase = log2f(((float)(2 * i2) + 102.4f) / 358.4f);
        float sgn = (col & 1) ? 1.0f : -1.0f;
#pragma unroll
        for (int reg = 0; reg < 16; ++reg) {
          int rmap = (reg & 3) + 8 * (reg >> 2) + 4 * lh;
          float pos = (float)(srow0 + rmap);
          float ang = pos * inv_freq;
          float sn = sinf(ang), cs = cosf(ang);
          float scl = exp2f(esgn * pos * (1.0f / 512.0f) * lbase);
          float x = acc[nt][reg];
          float xp = __shfl_xor(x, 1);
          vals[nt][reg] = (_Float16)(x * (cs * scl) + sgn * xp * (sn * scl));
        }
      }
      __syncthreads();  // prior wsel's stg consumers done
#pragma unroll
      for (int nt = 0; nt < 4; ++nt) {
        int col = nbase + nt * 32 + l31;
        int c = col >> 3;
#pragma unroll
        for (int reg = 0; reg < 16; ++reg) {
          int row = mtile * 32 + (reg & 3) + 8 * (reg >> 2) + 4 * lh;
          int p = c ^ (row & 31);
          ((_Float16*)(stg + row * 512 + p * 16))[col & 7] = vals[nt][reg];
        }
      }
      __syncthreads();  // stg ready
      // coalesced store: 8 lanes cover 128B of one row
#pragma unroll
      for (int u = 0; u < 8; ++u) {
        int id = u * 256 + tid;
        int row = id >> 5, c = id & 31;
        int p = c ^ (row & 31);
        uint4 v = *(const uint4*)(stg + row * 512 + p * 16);
        *(uint4*)&o[(long)(m0 + row) * HD + c * 8] = v;
      }
    } else {
      // V: transpose through LDS -> VT[bn][h][s]
      __syncthreads();  // all MFMA xs reads + wsel=1 stg reads done
      _Float16 (*vt)[72] = (_Float16(*)[72])smem;
#pragma unroll
      for (int nt = 0; nt < 4; ++nt) {
        int h = nbase + nt * 32 + l31;
#pragma unroll
        for (int g = 0; g < 4; ++g) {
          half4 h4;
#pragma unroll
          for (int r = 0; r < 4; ++r) h4[r] = (_Float16)acc[nt][4 * g + r];
          *(half4*)&vt[h][mtile * 32 + 8 * g + 4 * lh] = h4;
        }
      }
      __syncthreads();
      const int sblk = m0 & (S_LEN - 1);
#pragma unroll
      for (int u = 0; u < 8; ++u) {
        int id = u * 256 + tid;
        int h = id >> 3, sj = (id & 7) * 8;
        *(uint4*)&VT[((long)bn * HD + h) * S_LEN + sblk + sj] = *(const uint4*)&vt[h][sj];
      }
    }
  }
}

// ---------------- Kernel 1: retention (unchanged from round 4) ----------------
__global__ __launch_bounds__(256) void retention_kernel(
    const _Float16* __restrict__ Q, const _Float16* __restrict__ K,
    const _Float16* __restrict__ VT, float* __restrict__ out) {
  __shared__ __align__(16) unsigned char smem[65536];
  unsigned char* ksb = smem;            // 32KB: 64 t-rows x 512B, p = c ^ (t&31)
  unsigned char* vsb = smem + 32768;    // 32KB: 256 h-rows x 128B, p = c ^ (h&7)
  _Float16 (*sc)[72] = (_Float16(*)[72])smem;  // S^T->S round-trip, aliases ksb

  const int tid = threadIdx.x;
  const int lane = tid & 63;
  const int w = tid >> 6;
  const int l31 = lane & 31;
  const int lh = lane >> 5;
  const int qtile = w >> 1;
  const int ttile = w & 1;
  const int hhalf = w & 1;

  const int L = blockIdx.x;
  const int head = L & 15;
  const int qt = 31 - (L >> 4);
  const int q0 = qt * 64;

  const _Float16* Qh = Q + (long)head * S_LEN * HD;
  const _Float16* Kh = K + (long)head * S_LEN * HD;
  const _Float16* VTh = VT + (long)head * HD * S_LEN;

  half8 qf[16];
  {
    const _Float16* qrow = Qh + (long)(q0 + qtile * 32 + l31) * HD + lh * 8;
#pragma unroll
    for (int ks16 = 0; ks16 < 16; ++ks16)
      qf[ks16] = *(const half8*)(qrow + ks16 * 16);
  }

  floatx16 acc[4];
#pragma unroll
  for (int nt = 0; nt < 4; ++nt)
#pragma unroll
    for (int e = 0; e < 16; ++e) acc[nt][e] = 0.f;

  const float LG = -0.0458036896f;  // log2(0.96875)

  for (int kt = 0; kt <= qt; ++kt) {
    const int t0 = kt * 64;
#pragma unroll
    for (int j = 0; j < 8; ++j) {
      int li = w * 8 + j;
      int row = li * 2 + lh;
      int c = l31 ^ (row & 31);
      gl_lds16(Kh + (long)(t0 + row) * HD + c * 8, ksb + li * 1024);
    }
#pragma unroll
    for (int j = 0; j < 8; ++j) {
      int li = w * 8 + j;
      int row = li * 8 + (lane >> 3);
      int c = (lane & 7) ^ (row & 7);
      gl_lds16(VTh + (long)row * S_LEN + t0 + c * 8, vsb + li * 1024);
    }
    __syncthreads();  // B1: staging complete

    floatx16 s;
#pragma unroll
    for (int e = 0; e < 16; ++e) s[e] = 0.f;
    {
      const unsigned char* kbase = ksb + (ttile * 32 + l31) * 512;
#pragma unroll
      for (int ks16 = 0; ks16 < 16; ++ks16) {
        int p = (ks16 * 2 + lh) ^ l31;
        half8 a = *(const half8*)(kbase + p * 16);
        s = __builtin_amdgcn_mfma_f32_32x32x16_f16(a, qf[ks16], s, 0, 0, 0);
      }
    }
    __syncthreads();  // B2: ks reads done before sc overwrites ksb

    {
      const int qg = q0 + qtile * 32 + l31;
      const int tb = t0 + ttile * 32 + 4 * lh;
#pragma unroll
      for (int g = 0; g < 4; ++g) {
        half4 h4;
#pragma unroll
        for (int r = 0; r < 4; ++r) {
          int d = qg - (tb + 8 * g + r);
          float wv = (d >= 0) ? exp2f((float)d * LG) : 0.f;
          h4[r] = (_Float16)(s[4 * g + r] * wv);
        }
        *(half4*)&sc[qtile * 32 + l31][ttile * 32 + 4 * lh + 8 * g] = h4;
      }
    }
    __syncthreads();  // B3: sc ready

#pragma unroll
    for (int kst = 0; kst < 4; ++kst) {
      half8 a = *(const half8*)&sc[qtile * 32 + l31][kst * 16 + lh * 8];
#pragma unroll
      for (int nt = 0; nt < 4; ++nt) {
        int h = hhalf * 128 + nt * 32 + l31;
        int p = (kst * 2 + lh) ^ (h & 7);
        half8 b = *(const half8*)(vsb + h * 128 + p * 16);
        acc[nt] = __builtin_amdgcn_mfma_f32_32x32x16_f16(a, b, acc[nt], 0, 0, 0);
      }
    }
    __syncthreads();  // B4: sc/vsb reads done before next staging
  }

  const long rbase = (long)head * S_LEN + q0 + qtile * 32;
#pragma unroll
  for (int nt = 0; nt < 4; ++nt) {
    int col = hhalf * 128 + nt * 32 + l31;
#pragma unroll
    for (int reg = 0; reg < 16; ++reg) {
      int rmap = (reg & 3) + 8 * (reg >> 2) + 4 * lh;
      out[(rbase + rmap) * HD + col] = acc[nt][reg];
    }
  }
}

extern "C" void kernel_launch(void* const* d_in, const int* in_sizes, int n_in,
                              void* d_out, int out_size, void* d_ws, size_t ws_size,
                              hipStream_t stream) {
  const float* X  = (const float*)d_in[0];
  const float* WQ = (const float*)d_in[1];
  const float* WK = (const float*)d_in[2];
  const float* WV = (const float*)d_in[3];
  float* out = (float*)d_out;

  _Float16* Qh = (_Float16*)d_ws;
  _Float16* Kh = Qh + (size_t)BN * S_LEN * HD;
  _Float16* VTh = Kh + (size_t)BN * S_LEN * HD;
  _Float16* WT = VTh + (size_t)BN * S_LEN * HD;

  wprep_kernel<<<dim3(16, 3), dim3(256), 0, stream>>>(WQ, WK, WV, WT);
  gemm_qkv_kernel<<<dim3((BN * S_LEN) / 64), dim3(256), 0, stream>>>(
      X, WT, Qh, Kh, VTh);
  retention_kernel<<<dim3(512), dim3(256), 0, stream>>>(Qh, Kh, VTh, out);
}

// Round 6
// 285.324 us; speedup vs baseline: 1.4976x; 1.4976x over previous
//
#include <hip/hip_runtime.h>
#include <hip/hip_bf16.h>

// SimpleRetention on MI355X — round 6.
// K0: reverted to round-4 structure (112 µs known): X staged once (swizzled
//     LDS), WT B-frags register-double-buffered from L2, 32x32x16 MFMA, xpos
//     epilogue with direct scalar stores — now reg-outer/nt-inner so the two
//     64B halves of each 128B line issue back-to-back (merge in L2).
// K1: retention rewrite: 512-thr blocks (8 waves: qtile x ttile x hhalf).
//     K-tile double-buffered via global_load_lds (2x32KB, full 64KB LDS),
//     ONE barrier/iter. S^T=K*Q^T; C->A layout transform done IN REGISTERS
//     via shfl_xor(32) lane-pair exchange (no LDS round-trip). PV k-split by
//     ttile (partial acc), V B-frags direct 16B global loads (L2-resident),
//     cross-ttile reduction through LDS once at epilogue.

#define S_LEN 2048
#define HD 256
#define BN 16

typedef _Float16 half8 __attribute__((ext_vector_type(8)));
typedef _Float16 half4 __attribute__((ext_vector_type(4)));
typedef float floatx16 __attribute__((ext_vector_type(16)));

__device__ __forceinline__ void gl_lds16(const void* g, void* l) {
  __builtin_amdgcn_global_load_lds(
      (const __attribute__((address_space(1))) unsigned int*)(unsigned long long)g,
      (__attribute__((address_space(3))) unsigned int*)(unsigned int)(unsigned long long)l,
      16, 0, 0);
}

// ---------------- Kernel P: W transpose fp32 -> f16 [w][n][k] ----------------
__global__ __launch_bounds__(256) void wprep_kernel(
    const float* __restrict__ WQ, const float* __restrict__ WK,
    const float* __restrict__ WV, _Float16* __restrict__ WT) {
  __shared__ _Float16 trans[64][72];
  const int tid = threadIdx.x;
  const int w = blockIdx.y;
  const int tk = (blockIdx.x & 3) * 64;
  const int tn = (blockIdx.x >> 2) * 64;
  const float* W = (w == 0) ? WQ : (w == 1) ? WK : WV;
#pragma unroll
  for (int u = 0; u < 4; ++u) {
    int idx = u * 256 + tid;
    int k = idx >> 4;
    int nq = (idx & 15) * 4;
    float4 v = *(const float4*)&W[(tk + k) * HD + tn + nq];
    trans[nq + 0][k] = (_Float16)v.x;
    trans[nq + 1][k] = (_Float16)v.y;
    trans[nq + 2][k] = (_Float16)v.z;
    trans[nq + 3][k] = (_Float16)v.w;
  }
  __syncthreads();
#pragma unroll
  for (int u = 0; u < 2; ++u) {
    int idx = u * 256 + tid;
    int n = idx >> 3;
    int kq = (idx & 7) * 8;
    *(uint4*)&WT[((long)w * HD + tn + n) * HD + tk + kq] = *(const uint4*)&trans[n][kq];
  }
}

// ---------------- Kernel 0: fused QKV projection + xpos (round-4) -----------
__global__ __launch_bounds__(256) void gemm_qkv_kernel(
    const float* __restrict__ X, const _Float16* __restrict__ WT,
    _Float16* __restrict__ Q, _Float16* __restrict__ K,
    _Float16* __restrict__ VT) {
  __shared__ __align__(16) unsigned char smem[36864];

  const int tid = threadIdx.x;
  const int lane = tid & 63;
  const int w = tid >> 6;
  const int l31 = lane & 31;
  const int lh = lane >> 5;
  const int m0 = blockIdx.x * 64;
  const int mtile = w & 1;
  const int nhalf = w >> 1;

  // stage X (64 rows x 256 fp32) -> f16 swizzled: chunk p = c ^ (row&31)
#pragma unroll
  for (int i = 0; i < 8; ++i) {
    int id = i * 256 + tid;
    int row = id >> 5, c = id & 31;
    int p = c ^ (row & 31);
    const float4* s = (const float4*)&X[(long)(m0 + row) * HD + c * 8];
    float4 v0 = s[0], v1 = s[1];
    half8 h;
    h[0] = (_Float16)v0.x; h[1] = (_Float16)v0.y;
    h[2] = (_Float16)v0.z; h[3] = (_Float16)v0.w;
    h[4] = (_Float16)v1.x; h[5] = (_Float16)v1.y;
    h[6] = (_Float16)v1.z; h[7] = (_Float16)v1.w;
    *(half8*)(smem + row * 512 + p * 16) = h;
  }
  __syncthreads();

  const int bn = m0 >> 11;
  const int mrow = mtile * 32 + l31;
  const int nbase = nhalf * 128;

  for (int wsel = 0; wsel < 3; ++wsel) {
    const _Float16* Wb = WT + (long)wsel * HD * HD;
    floatx16 acc[4];
#pragma unroll
    for (int nt = 0; nt < 4; ++nt)
#pragma unroll
      for (int e = 0; e < 16; ++e) acc[nt][e] = 0.f;

    half8 bcur[4], bnxt[4];
#pragma unroll
    for (int nt = 0; nt < 4; ++nt)
      bcur[nt] = *(const half8*)(Wb + (long)(nbase + nt * 32 + l31) * HD + lh * 8);
#pragma unroll
    for (int ks16 = 0; ks16 < 16; ++ks16) {
      int p = (ks16 * 2 + lh) ^ l31;
      half8 af = *(const half8*)(smem + mrow * 512 + p * 16);
      if (ks16 < 15) {
#pragma unroll
        for (int nt = 0; nt < 4; ++nt)
          bnxt[nt] = *(const half8*)(Wb + (long)(nbase + nt * 32 + l31) * HD +
                                     (ks16 + 1) * 16 + lh * 8);
      }
#pragma unroll
      for (int nt = 0; nt < 4; ++nt)
        acc[nt] = __builtin_amdgcn_mfma_f32_32x32x16_f16(af, bcur[nt], acc[nt], 0, 0, 0);
#pragma unroll
      for (int nt = 0; nt < 4; ++nt) bcur[nt] = bnxt[nt];
    }

    if (wsel < 2) {
      // xpos in C-layout. reg-outer / nt-inner: the two 64B halves of each
      // 128B line (nt pairs) issue back-to-back -> L2 write merge.
      _Float16* o = wsel ? K : Q;
      const float esgn = wsel ? -1.0f : 1.0f;  // Q upscale, K downscale
      const int srow0 = (m0 & (S_LEN - 1)) + mtile * 32;
      float ifr[4], lb[4];
#pragma unroll
      for (int nt = 0; nt < 4; ++nt) {
        int col = nbase + nt * 32 + l31;
        int i2 = col >> 1;
        ifr[nt] = exp2f(-(float)i2 * (13.287712379549449f / 128.0f));
        lb[nt] = log2f(((float)(2 * i2) + 102.4f) / 358.4f);
      }
      const float sgn = (l31 & 1) ? 1.0f : -1.0f;
#pragma unroll
      for (int reg = 0; reg < 16; ++reg) {
        int rmap = (reg & 3) + 8 * (reg >> 2) + 4 * lh;
        float pos = (float)(srow0 + rmap);
        long rowoff = (long)(m0 + mtile * 32 + rmap) * HD;
#pragma unroll
        for (int nt = 0; nt < 4; ++nt) {
          int col = nbase + nt * 32 + l31;
          float ang = pos * ifr[nt];
          float sn = sinf(ang), cs = cosf(ang);
          float scl = exp2f(esgn * pos * (1.0f / 512.0f) * lb[nt]);
          float x = acc[nt][reg];
          float xp = __shfl_xor(x, 1);
          o[rowoff + col] = (_Float16)(x * (cs * scl) + sgn * xp * (sn * scl));
        }
      }
    } else {
      // V: transpose through LDS -> VT[bn][h][s]
      __syncthreads();
      _Float16 (*vt)[72] = (_Float16(*)[72])smem;
#pragma unroll
      for (int nt = 0; nt < 4; ++nt) {
        int h = nbase + nt * 32 + l31;
#pragma unroll
        for (int g = 0; g < 4; ++g) {
          half4 h4;
#pragma unroll
          for (int r = 0; r < 4; ++r) h4[r] = (_Float16)acc[nt][4 * g + r];
          *(half4*)&vt[h][mtile * 32 + 8 * g + 4 * lh] = h4;
        }
      }
      __syncthreads();
      const int sblk = m0 & (S_LEN - 1);
#pragma unroll
      for (int u = 0; u < 8; ++u) {
        int id = u * 256 + tid;
        int h = id >> 3, sj = (id & 7) * 8;
        *(uint4*)&VT[((long)bn * HD + h) * S_LEN + sblk + sj] = *(const uint4*)&vt[h][sj];
      }
    }
  }
}

// ---------------- Kernel 1: retention, 512 thr, 1 barrier/iter ---------------
__global__ __launch_bounds__(512, 2) void retention_kernel(
    const _Float16* __restrict__ Q, const _Float16* __restrict__ K,
    const _Float16* __restrict__ VT, float* __restrict__ out) {
  __shared__ __align__(16) unsigned char smem[65536];  // K tile double buffer

  const int tid = threadIdx.x;
  const int lane = tid & 63;
  const int w = tid >> 6;          // 0..7
  const int l31 = lane & 31;
  const int lh = lane >> 5;
  const int qtile = w >> 2;        // 0,1: q rows qtile*32..+31
  const int ttile = (w >> 1) & 1;  // 0,1: this wave's k(t)-half
  const int hhalf = w & 1;         // 0,1: PV h-half

  const int L = blockIdx.x;
  const int head = L & 15;
  const int qt = 31 - (L >> 4);    // big q-tiles first
  const int q0 = qt * 64;

  const _Float16* Qh = Q + (long)head * S_LEN * HD;
  const _Float16* Kh = K + (long)head * S_LEN * HD;
  const _Float16* VTh = VT + (long)head * HD * S_LEN;

  // Q register-resident as B-frags: n = q row, k = h
  half8 qf[16];
  {
    const _Float16* qrow = Qh + (long)(q0 + qtile * 32 + l31) * HD + lh * 8;
#pragma unroll
    for (int ks16 = 0; ks16 < 16; ++ks16)
      qf[ks16] = *(const half8*)(qrow + ks16 * 16);
  }

  floatx16 acc[4];
#pragma unroll
  for (int nt = 0; nt < 4; ++nt)
#pragma unroll
    for (int e = 0; e < 16; ++e) acc[nt][e] = 0.f;

  const float LG = -0.0458036896f;  // log2(0.96875)

  // preload K tile 0 into buffer 0 (rows swizzled: chunk p = c ^ (row&31))
#pragma unroll
  for (int j = 0; j < 4; ++j) {
    int li = w * 4 + j;
    int row = li * 2 + lh;
    int c = l31 ^ (row & 31);
    gl_lds16(Kh + (long)row * HD + c * 8, smem + li * 1024);
  }
  __syncthreads();

  for (int kt = 0; kt <= qt; ++kt) {
    const int t0 = kt * 64;
    const unsigned char* kcur = smem + (kt & 1) * 32768;
    // diagonal tile: wave (qtile0, ttile1) is fully causal-masked
    const bool active = !(kt == qt && ttile == 1 && qtile == 0);

    // V B-frags direct from global (L2/L3-resident): issued BEFORE prefetch
    // so waiting on them doesn't drain the (younger) prefetch. Consumed a
    // whole QK-phase later.
    half8 vb[8];
    if (active) {
      const _Float16* vbase =
          VTh + (long)(hhalf * 128 + l31) * S_LEN + t0 + ttile * 32 + lh * 8;
#pragma unroll
      for (int kst = 0; kst < 2; ++kst)
#pragma unroll
        for (int nt = 0; nt < 4; ++nt)
          vb[kst * 4 + nt] = *(const half8*)(vbase + (long)(nt * 32) * S_LEN + kst * 16);
    }

    // prefetch next K tile into the other buffer
    if (kt < qt) {
      unsigned char* knxt = smem + ((kt + 1) & 1) * 32768;
#pragma unroll
      for (int j = 0; j < 4; ++j) {
        int li = w * 4 + j;
        int row = li * 2 + lh;
        int c = l31 ^ (row & 31);
        gl_lds16(Kh + (long)(t0 + 64 + row) * HD + c * 8, knxt + li * 1024);
      }
    }

    if (active) {
      // S^T = K * Q^T  (m = t, n = q): C-layout cols = q = l31
      floatx16 s;
#pragma unroll
      for (int e = 0; e < 16; ++e) s[e] = 0.f;
      const unsigned char* kbase = kcur + (ttile * 32 + l31) * 512;
#pragma unroll
      for (int ks16 = 0; ks16 < 16; ++ks16) {
        int p = (ks16 * 2 + lh) ^ l31;
        half8 a = *(const half8*)(kbase + p * 16);
        s = __builtin_amdgcn_mfma_f32_32x32x16_f16(a, qf[ks16], s, 0, 0, 0);
      }

      // decay+mask in regs, then lane-pair exchange (shfl_xor 32) to build
      // PV A-frags — no LDS round-trip, no barriers.
      const int q = q0 + qtile * 32 + l31;
      const int tb = t0 + ttile * 32;
      float sd[16];
#pragma unroll
      for (int r = 0; r < 16; ++r) {
        int t = tb + (r & 3) + 8 * (r >> 2) + 4 * lh;
        int d = q - t;
        sd[r] = (d >= 0) ? s[r] * exp2f((float)d * LG) : 0.f;
      }
      float pr[16];
#pragma unroll
      for (int r = 0; r < 16; ++r) pr[r] = __shfl_xor(sd[r], 32);
      half8 af[2];
#pragma unroll
      for (int kst = 0; kst < 2; ++kst) {
        int b0 = 8 * kst, b1 = 8 * kst + 4;
#pragma unroll
        for (int j = 0; j < 4; ++j) {
          float lo = lh ? pr[b1 + j] : sd[b0 + j];
          float hi = lh ? sd[b1 + j] : pr[b0 + j];
          af[kst][j] = (_Float16)lo;
          af[kst][4 + j] = (_Float16)hi;
        }
      }

      // PV partial over this wave's t-half
#pragma unroll
      for (int kst = 0; kst < 2; ++kst)
#pragma unroll
        for (int nt = 0; nt < 4; ++nt)
          acc[nt] = __builtin_amdgcn_mfma_f32_32x32x16_f16(af[kst], vb[kst * 4 + nt],
                                                           acc[nt], 0, 0, 0);
    }
    __syncthreads();  // all ks reads done; prefetch drained -> buffers rotate
  }

  // cross-ttile partial-acc reduction through LDS (K buffers are free now)
  {
    float* red = (float*)smem;
    float* myreg = red + (qtile * 2 + hhalf) * 4096 + lane;
    if (ttile == 1) {
#pragma unroll
      for (int nt = 0; nt < 4; ++nt)
#pragma unroll
        for (int r = 0; r < 16; ++r)
          myreg[nt * 1024 + r * 64] = acc[nt][r];
    }
    __syncthreads();
    if (ttile == 0) {
#pragma unroll
      for (int nt = 0; nt < 4; ++nt)
#pragma unroll
        for (int r = 0; r < 16; ++r)
          acc[nt][r] += myreg[nt * 1024 + r * 64];
      const long rbase = (long)head * S_LEN + q0 + qtile * 32;
#pragma unroll
      for (int r = 0; r < 16; ++r) {
        int rmap = (r & 3) + 8 * (r >> 2) + 4 * lh;
#pragma unroll
        for (int nt = 0; nt < 4; ++nt)
          out[(rbase + rmap) * HD + hhalf * 128 + nt * 32 + l31] = acc[nt][r];
      }
    }
  }
}

extern "C" void kernel_launch(void* const* d_in, const int* in_sizes, int n_in,
                              void* d_out, int out_size, void* d_ws, size_t ws_size,
                              hipStream_t stream) {
  const float* X  = (const float*)d_in[0];
  const float* WQ = (const float*)d_in[1];
  const float* WK = (const float*)d_in[2];
  const float* WV = (const float*)d_in[3];
  float* out = (float*)d_out;

  _Float16* Qh = (_Float16*)d_ws;
  _Float16* Kh = Qh + (size_t)BN * S_LEN * HD;
  _Float16* VTh = Kh + (size_t)BN * S_LEN * HD;
  _Float16* WT = VTh + (size_t)BN * S_LEN * HD;

  wprep_kernel<<<dim3(16, 3), dim3(256), 0, stream>>>(WQ, WK, WV, WT);
  gemm_qkv_kernel<<<dim3((BN * S_LEN) / 64), dim3(256), 0, stream>>>(
      X, WT, Qh, Kh, VTh);
  retention_kernel<<<dim3(512), dim3(512), 0, stream>>>(Qh, Kh, VTh, out);
}